// Round 5
// baseline (244.402 us; speedup 1.0000x reference)
//
#include <hip/hip_runtime.h>

typedef __attribute__((ext_vector_type(8))) __bf16 bf16x8;
typedef __attribute__((ext_vector_type(4))) float f32x4;
typedef unsigned short u16;

#define MFMA16(a, b, c) __builtin_amdgcn_mfma_f32_16x16x32_bf16(a, b, c, 0, 0, 0)

__device__ __forceinline__ u16 f2bf(float f) {
    unsigned u = __float_as_uint(f);
    unsigned r = ((u >> 16) & 1u) + 0x7fffu;  // RNE
    return (u16)((u + r) >> 16);
}
__device__ __forceinline__ float bf2f(u16 h) {
    return __uint_as_float(((unsigned)h) << 16);
}
// LDS fragment, row stride 72 u16 (144 B, 16B-aligned): row=rtile+(lane&15)
__device__ __forceinline__ bf16x8 frag(const u16* base, int rtile, int lane, int kofs) {
    return *(const bf16x8*)(base + (rtile + (lane & 15)) * 72 + kofs + (lane >> 4) * 8);
}
// row stride 40 u16 (80 B, 16B-aligned) for 32-wide K tiles
__device__ __forceinline__ bf16x8 frag40(const u16* base, int rtile, int lane) {
    return *(const bf16x8*)(base + (rtile + (lane & 15)) * 40 + (lane >> 4) * 8);
}

// ---------------------------------------------------------------------------
// Fused partials over k-quarters (blockIdx.y = ks in 0..3):
//   Qp[ks]=x*Wq^T, Kp[ks]=x*Wk^T, fcp[ks]=x*W1^T (3-product bf16 split)
// 1024 blocks, 30.7 KB LDS -> 4 blocks/CU, 16 waves/CU. Chunk K = 32.
// ---------------------------------------------------------------------------
__global__ __launch_bounds__(256, 4) void qkf_kernel(
    const float* __restrict__ x, const float* __restrict__ Wq,
    const float* __restrict__ Wk, const float* __restrict__ W1,
    float* __restrict__ Qp, float* __restrict__ Kp, float* __restrict__ fcp)
{
    __shared__ __align__(16) u16 SM[6 * 2560];   // 64 rows x 40 u16 per array
    u16* Xh  = SM;
    u16* Xl  = SM + 2560;
    u16* Wqh = SM + 2 * 2560;
    u16* Wkh = SM + 3 * 2560;
    u16* W1h = SM + 4 * 2560;
    u16* W1l = SM + 5 * 2560;

    const int tid  = threadIdx.x;
    const int lane = tid & 63;
    const int wv   = tid >> 6;
    const int r0   = wv * 16;
    const long row0 = (long)blockIdx.x * 64;
    const int ks   = blockIdx.y;
    const int kb   = ks * 256;
    const long sOf = (long)ks * 1048576;

    const f32x4 zero = {0.f, 0.f, 0.f, 0.f};
    f32x4 qa[4], ka[4], fa[4];
#pragma unroll
    for (int i = 0; i < 4; ++i) { qa[i] = zero; ka[i] = zero; fa[i] = zero; }

    const int sr  = tid >> 2;        // staging row 0..63
    const int skq = (tid & 3) * 8;   // staging k base 0,8,16,24

    float4 xv[2], qv[2], kv[2], w1v[2];
#define QKF_LOAD(K0)                                                          \
    {                                                                         \
        _Pragma("unroll")                                                     \
        for (int h = 0; h < 2; ++h) {                                         \
            int col = (K0) + skq + h * 4;                                     \
            xv[h]  = *(const float4*)(x  + (row0 + sr) * 1024 + col);         \
            qv[h]  = *(const float4*)(Wq + (long)sr * 1024 + col);            \
            kv[h]  = *(const float4*)(Wk + (long)sr * 1024 + col);            \
            w1v[h] = *(const float4*)(W1 + (long)sr * 1024 + col);            \
        }                                                                     \
    }

    QKF_LOAD(kb)
    for (int ch = 0; ch < 8; ++ch) {
        if (ch) __syncthreads();
#pragma unroll
        for (int h = 0; h < 2; ++h) {
            int o = sr * 40 + skq + h * 4;
            ushort4 hx, lx;
            hx.x = f2bf(xv[h].x); lx.x = f2bf(xv[h].x - bf2f(hx.x));
            hx.y = f2bf(xv[h].y); lx.y = f2bf(xv[h].y - bf2f(hx.y));
            hx.z = f2bf(xv[h].z); lx.z = f2bf(xv[h].z - bf2f(hx.z));
            hx.w = f2bf(xv[h].w); lx.w = f2bf(xv[h].w - bf2f(hx.w));
            *(ushort4*)&Xh[o] = hx;
            *(ushort4*)&Xl[o] = lx;
            ushort4 hq;
            hq.x = f2bf(qv[h].x); hq.y = f2bf(qv[h].y);
            hq.z = f2bf(qv[h].z); hq.w = f2bf(qv[h].w);
            *(ushort4*)&Wqh[o] = hq;
            ushort4 hk;
            hk.x = f2bf(kv[h].x); hk.y = f2bf(kv[h].y);
            hk.z = f2bf(kv[h].z); hk.w = f2bf(kv[h].w);
            *(ushort4*)&Wkh[o] = hk;
            ushort4 hw, lw;
            hw.x = f2bf(w1v[h].x); lw.x = f2bf(w1v[h].x - bf2f(hw.x));
            hw.y = f2bf(w1v[h].y); lw.y = f2bf(w1v[h].y - bf2f(hw.y));
            hw.z = f2bf(w1v[h].z); lw.z = f2bf(w1v[h].z - bf2f(hw.z));
            hw.w = f2bf(w1v[h].w); lw.w = f2bf(w1v[h].w - bf2f(hw.w));
            *(ushort4*)&W1h[o] = hw;
            *(ushort4*)&W1l[o] = lw;
        }
        __syncthreads();
        if (ch < 7) QKF_LOAD(kb + (ch + 1) * 32)
        {
            bf16x8 ah = frag40(Xh, r0, lane);
            bf16x8 al = frag40(Xl, r0, lane);
#pragma unroll
            for (int ct = 0; ct < 4; ++ct) {
                qa[ct] = MFMA16(ah, frag40(Wqh, ct * 16, lane), qa[ct]);
                ka[ct] = MFMA16(ah, frag40(Wkh, ct * 16, lane), ka[ct]);
                bf16x8 bh = frag40(W1h, ct * 16, lane);
                fa[ct] = MFMA16(ah, bh, fa[ct]);
                fa[ct] = MFMA16(al, bh, fa[ct]);
                fa[ct] = MFMA16(ah, frag40(W1l, ct * 16, lane), fa[ct]);
            }
        }
    }
#undef QKF_LOAD

    const int rr = r0 + (lane >> 4) * 4;
    const int cc = lane & 15;
#pragma unroll
    for (int ct = 0; ct < 4; ++ct)
#pragma unroll
        for (int g = 0; g < 4; ++g) {
            long o = sOf + (row0 + rr + g) * 64 + ct * 16 + cc;
            Qp[o]  = qa[ct][g];
            Kp[o]  = ka[ct][g];
            fcp[o] = fa[ct][g];
        }
}

// ---------------------------------------------------------------------------
// Sp[ks][b][j][d] = sum_{n in ks-slice} K[b,n,j] * x[b,n,d]
// K = sum of 4 fp32 slabs at staging. grid (16,8,8) = 1024 blocks (4/CU).
// ---------------------------------------------------------------------------
__global__ __launch_bounds__(256, 4) void s_kernel(
    const float* __restrict__ Kp, const float* __restrict__ x,
    float* __restrict__ Sp)
{
    __shared__ __align__(16) u16 Kt[64 * 72];
    __shared__ __align__(16) u16 Xt[64 * 72];

    const int tid = threadIdx.x, lane = tid & 63, wv = tid >> 6;
    const int dt = blockIdx.x, ks = blockIdx.y, b = blockIdx.z;
    const int n0 = ks * 256, d0 = dt * 64;

    const float* Kq = Kp + ((long)b * 2048 + n0) * 64;
    const float* xp = x  + ((long)b * 2048 + n0) * 1024 + d0;

    const f32x4 zero = {0.f, 0.f, 0.f, 0.f};
    f32x4 acc[4];
#pragma unroll
    for (int i = 0; i < 4; ++i) acc[i] = zero;

    float4 kf[4], xv[4];
#define SK_LOAD(NB)                                                           \
    {                                                                         \
        _Pragma("unroll")                                                     \
        for (int i = 0; i < 4; ++i) {                                         \
            const float* kp0 = Kq + (long)((NB) + lane) * 64 + wv * 16 + i * 4; \
            float4 a = *(const float4*)kp0;                                   \
            _Pragma("unroll")                                                 \
            for (int s = 1; s < 4; ++s) {                                     \
                float4 c = *(const float4*)(kp0 + (long)s * 1048576);         \
                a.x += c.x; a.y += c.y; a.z += c.z; a.w += c.w;               \
            }                                                                 \
            kf[i] = a;                                                        \
            xv[i] = *(const float4*)(xp + (long)((NB) + lane) * 1024 + wv * 16 + i * 4); \
        }                                                                     \
    }

    SK_LOAD(0)
    for (int ch = 0; ch < 4; ++ch) {
        if (ch) __syncthreads();
#pragma unroll
        for (int i = 0; i < 4; ++i) {
            Kt[(wv * 16 + i * 4 + 0) * 72 + lane] = f2bf(kf[i].x);
            Kt[(wv * 16 + i * 4 + 1) * 72 + lane] = f2bf(kf[i].y);
            Kt[(wv * 16 + i * 4 + 2) * 72 + lane] = f2bf(kf[i].z);
            Kt[(wv * 16 + i * 4 + 3) * 72 + lane] = f2bf(kf[i].w);
            Xt[(wv * 16 + i * 4 + 0) * 72 + lane] = f2bf(xv[i].x);
            Xt[(wv * 16 + i * 4 + 1) * 72 + lane] = f2bf(xv[i].y);
            Xt[(wv * 16 + i * 4 + 2) * 72 + lane] = f2bf(xv[i].z);
            Xt[(wv * 16 + i * 4 + 3) * 72 + lane] = f2bf(xv[i].w);
        }
        __syncthreads();
        if (ch < 3) SK_LOAD((ch + 1) * 64)
#pragma unroll
        for (int kk = 0; kk < 64; kk += 32) {
            bf16x8 a = frag(Kt, wv * 16, lane, kk);
#pragma unroll
            for (int ct = 0; ct < 4; ++ct)
                acc[ct] = MFMA16(a, frag(Xt, ct * 16, lane, kk), acc[ct]);
        }
    }
#undef SK_LOAD

    float* C = Sp + ((long)ks * 8 + b) * 65536 + d0;
    const int rr = wv * 16 + (lane >> 4) * 4;
    const int cc = lane & 15;
#pragma unroll
    for (int ct = 0; ct < 4; ++ct)
#pragma unroll
        for (int g = 0; g < 4; ++g)
            C[(long)(rr + g) * 1024 + ct * 16 + cc] = acc[ct][g];
}

// ---------------------------------------------------------------------------
// 64x64 MFMA NT-GEMM (used for G and PBT): C = sum_k (sum A_s)*(sum B_s)
// AMODE 0: fp32 row-major. BMODE 0: fp32 row-major; 2: fp32 transposed [k][n].
// ---------------------------------------------------------------------------
template <int AMODE, int BMODE, int ASLAB, int BSLAB>
__global__ __launch_bounds__(256) void mm_nt(
    const void* __restrict__ Ap, int lda, long bsA, long slabA,
    const void* __restrict__ Bp, int ldb, long bsB, long slabB,
    float* __restrict__ Cp, int ldc, long bsC, long splitC,
    int Kred, int nksplit)
{
    __shared__ __align__(16) u16 SMEM[2 * 4608];
    u16* Ah = SMEM;
    u16* Bh = SMEM + 4608;

    const int tid = threadIdx.x, lane = tid & 63, wv = tid >> 6;
    const int bm = blockIdx.x, bn = blockIdx.y;
    const int batch = blockIdx.z / nksplit;
    const int ks = blockIdx.z % nksplit;
    const int Kper = Kred / nksplit;
    const long kOff = (long)ks * Kper;

    const int r4 = tid >> 4, k4 = (tid & 15) * 4;

    const f32x4 zero = {0.f, 0.f, 0.f, 0.f};
    f32x4 acc[4];
#pragma unroll
    for (int i = 0; i < 4; ++i) acc[i] = zero;

    float4 fva[4], fvb[4];
    float  tvb[16];

#define MM_LOADA(K0)                                                          \
    {                                                                         \
        const float* A = (const float*)Ap + (long)batch * bsA                 \
                       + (long)bm * 64 * lda + (K0);                          \
        _Pragma("unroll")                                                     \
        for (int i = 0; i < 4; ++i) {                                         \
            const float* p = A + (long)(r4 + i * 16) * lda + k4;              \
            float4 v = *(const float4*)p;                                     \
            _Pragma("unroll")                                                 \
            for (int s = 1; s < ASLAB; ++s) {                                 \
                float4 w = *(const float4*)(p + (long)s * slabA);             \
                v.x += w.x; v.y += w.y; v.z += w.z; v.w += w.w;               \
            }                                                                 \
            fva[i] = v;                                                       \
        }                                                                     \
    }
#define MM_LOADB(K0)                                                          \
    if constexpr (BMODE == 0) {                                               \
        const float* Bq = (const float*)Bp + (long)batch * bsB                \
                        + (long)bn * 64 * ldb + (K0);                         \
        _Pragma("unroll")                                                     \
        for (int i = 0; i < 4; ++i) {                                         \
            const float* p = Bq + (long)(r4 + i * 16) * ldb + k4;             \
            float4 v = *(const float4*)p;                                     \
            _Pragma("unroll")                                                 \
            for (int s = 1; s < BSLAB; ++s) {                                 \
                float4 w = *(const float4*)(p + (long)s * slabB);             \
                v.x += w.x; v.y += w.y; v.z += w.z; v.w += w.w;               \
            }                                                                 \
            fvb[i] = v;                                                       \
        }                                                                     \
    } else {                                                                  \
        const float* Bq = (const float*)Bp + (long)batch * bsB                \
                        + (long)(K0) * ldb + (long)bn * 64;                   \
        _Pragma("unroll")                                                     \
        for (int i = 0; i < 16; ++i)                                          \
            tvb[i] = Bq[(long)((tid >> 6) + i * 4) * ldb + (tid & 63)];       \
    }

    MM_LOADA(kOff) MM_LOADB(kOff)
    for (int k0 = 0; k0 < Kper; k0 += 64) {
        if (k0) __syncthreads();
#pragma unroll
        for (int i = 0; i < 4; ++i) {
            int r = r4 + i * 16;
            ushort4 h;
            h.x = f2bf(fva[i].x); h.y = f2bf(fva[i].y);
            h.z = f2bf(fva[i].z); h.w = f2bf(fva[i].w);
            *(ushort4*)&Ah[r * 72 + k4] = h;
        }
        if constexpr (BMODE == 0) {
#pragma unroll
            for (int i = 0; i < 4; ++i) {
                int r = r4 + i * 16;
                ushort4 h;
                h.x = f2bf(fvb[i].x); h.y = f2bf(fvb[i].y);
                h.z = f2bf(fvb[i].z); h.w = f2bf(fvb[i].w);
                *(ushort4*)&Bh[r * 72 + k4] = h;
            }
        } else {
#pragma unroll
            for (int i = 0; i < 16; ++i)
                Bh[(tid & 63) * 72 + (tid >> 6) + i * 4] = f2bf(tvb[i]);
        }
        __syncthreads();
        if (k0 + 64 < Kper) { MM_LOADA(kOff + k0 + 64) MM_LOADB(kOff + k0 + 64) }
#pragma unroll
        for (int kk = 0; kk < 64; kk += 32) {
            bf16x8 ah = frag(Ah, wv * 16, lane, kk);
#pragma unroll
            for (int ct = 0; ct < 4; ++ct)
                acc[ct] = MFMA16(ah, frag(Bh, ct * 16, lane, kk), acc[ct]);
        }
    }
#undef MM_LOADA
#undef MM_LOADB

    float* C = Cp + (long)batch * bsC + (long)ks * splitC
             + (long)bm * 64 * ldc + (long)bn * 64;
    const int rr = wv * 16 + (lane >> 4) * 4;
    const int cc = lane & 15;
#pragma unroll
    for (int ct = 0; ct < 4; ++ct)
#pragma unroll
        for (int g = 0; g < 4; ++g)
            C[(long)(rr + g) * ldc + ct * 16 + cc] = acc[ct][g];
}

// ---------------------------------------------------------------------------
// Fused fc2 + output GEMM. Per block: 64 rows.
//   fc = sum_4 fcp + (sum_4 Qp)*(sum_16 PBp)^T      (fp32)
//   out[rows, 0..1023] = fc * W2^T                  (3-product split)
// ---------------------------------------------------------------------------
__global__ __launch_bounds__(256) void fcout_kernel(
    const float* __restrict__ Qp, const float* __restrict__ PBp,
    const float* __restrict__ fcp, const float* __restrict__ W2,
    float* __restrict__ out)
{
    __shared__ __align__(16) u16 Ah[4608];
    __shared__ __align__(16) u16 Al[4608];
    __shared__ __align__(16) u16 Bh[4608];
    __shared__ __align__(16) u16 Bl[4608];

    const int tid = threadIdx.x, lane = tid & 63, wv = tid >> 6;
    const long row0 = (long)blockIdx.x * 64;
    const int b = (int)(row0 >> 11);
    const int r4 = tid >> 2, c16 = (tid & 3) * 16;

    // Stage A = Qsum (bf16), B = PBsum (bf16)
#pragma unroll
    for (int h = 0; h < 4; ++h) {
        const float* qp0 = Qp + (row0 + r4) * 64 + c16 + h * 4;
        float4 v = *(const float4*)qp0;
#pragma unroll
        for (int s = 1; s < 4; ++s) {
            float4 w = *(const float4*)(qp0 + (long)s * 1048576);
            v.x += w.x; v.y += w.y; v.z += w.z; v.w += w.w;
        }
        ushort4 hh;
        hh.x = f2bf(v.x); hh.y = f2bf(v.y); hh.z = f2bf(v.z); hh.w = f2bf(v.w);
        *(ushort4*)&Ah[r4 * 72 + c16 + h * 4] = hh;
    }
    const float* pb = PBp + (long)b * 4096;
#pragma unroll
    for (int h = 0; h < 4; ++h) {
        float4 v = {0.f, 0.f, 0.f, 0.f};
#pragma unroll
        for (int s = 0; s < 16; ++s) {
            float4 w = *(const float4*)(pb + (long)s * 32768 + r4 * 64 + c16 + h * 4);
            v.x += w.x; v.y += w.y; v.z += w.z; v.w += w.w;
        }
        ushort4 hh;
        hh.x = f2bf(v.x); hh.y = f2bf(v.y); hh.z = f2bf(v.z); hh.w = f2bf(v.w);
        *(ushort4*)&Bh[r4 * 72 + c16 + h * 4] = hh;
    }
    __syncthreads();

    const f32x4 zero = {0.f, 0.f, 0.f, 0.f};
    f32x4 facc[4];
#pragma unroll
    for (int i = 0; i < 4; ++i) facc[i] = zero;
#pragma unroll
    for (int kk = 0; kk < 64; kk += 32) {
        bf16x8 ah = frag(Ah, wv * 16, lane, kk);
#pragma unroll
        for (int ct = 0; ct < 4; ++ct)
            facc[ct] = MFMA16(ah, frag(Bh, ct * 16, lane, kk), facc[ct]);
    }

    const int rr = wv * 16 + (lane >> 4) * 4;
    const int cc = lane & 15;
    __syncthreads();   // done reading Ah/Bh; reuse for fc hi/lo
#pragma unroll
    for (int ct = 0; ct < 4; ++ct)
#pragma unroll
        for (int g = 0; g < 4; ++g) {
            float v = facc[ct][g];
            long o = (row0 + rr + g) * 64 + ct * 16 + cc;
#pragma unroll
            for (int s = 0; s < 4; ++s) v += fcp[o + (long)s * 1048576];
            u16 h = f2bf(v);
            Ah[(rr + g) * 72 + ct * 16 + cc] = h;
            Al[(rr + g) * 72 + ct * 16 + cc] = f2bf(v - bf2f(h));
        }
    __syncthreads();

    // Sweep 16 W2 e-tiles with register prefetch
    float4 w2v[4];
#define W2_LOAD(E0)                                                           \
    {                                                                         \
        _Pragma("unroll")                                                     \
        for (int h = 0; h < 4; ++h)                                           \
            w2v[h] = *(const float4*)(W2 + (long)((E0) + r4) * 64 + c16 + h * 4); \
    }
    W2_LOAD(0)
    for (int et = 0; et < 16; ++et) {
        if (et) __syncthreads();
#pragma unroll
        for (int h = 0; h < 4; ++h) {
            ushort4 hh, ll;
            hh.x = f2bf(w2v[h].x); ll.x = f2bf(w2v[h].x - bf2f(hh.x));
            hh.y = f2bf(w2v[h].y); ll.y = f2bf(w2v[h].y - bf2f(hh.y));
            hh.z = f2bf(w2v[h].z); ll.z = f2bf(w2v[h].z - bf2f(hh.z));
            hh.w = f2bf(w2v[h].w); ll.w = f2bf(w2v[h].w - bf2f(hh.w));
            *(ushort4*)&Bh[r4 * 72 + c16 + h * 4] = hh;
            *(ushort4*)&Bl[r4 * 72 + c16 + h * 4] = ll;
        }
        __syncthreads();
        if (et < 15) W2_LOAD((et + 1) * 64)
        f32x4 oacc[4];
#pragma unroll
        for (int i = 0; i < 4; ++i) oacc[i] = zero;
#pragma unroll
        for (int kk = 0; kk < 64; kk += 32) {
            bf16x8 fh = frag(Ah, wv * 16, lane, kk);
            bf16x8 fl = frag(Al, wv * 16, lane, kk);
#pragma unroll
            for (int ct = 0; ct < 4; ++ct) {
                bf16x8 bh = frag(Bh, ct * 16, lane, kk);
                oacc[ct] = MFMA16(fh, bh, oacc[ct]);
                oacc[ct] = MFMA16(fl, bh, oacc[ct]);
                oacc[ct] = MFMA16(fh, frag(Bl, ct * 16, lane, kk), oacc[ct]);
            }
        }
#pragma unroll
        for (int ct = 0; ct < 4; ++ct)
#pragma unroll
            for (int g = 0; g < 4; ++g)
                out[(row0 + rr + g) * 1024 + et * 64 + ct * 16 + cc] = oacc[ct][g];
    }
#undef W2_LOAD
}

// ---------------------------------------------------------------------------
extern "C" void kernel_launch(void* const* d_in, const int* in_sizes, int n_in,
                              void* d_out, int out_size, void* d_ws, size_t ws_size,
                              hipStream_t stream)
{
    const float* x  = (const float*)d_in[0];
    const float* Wq = (const float*)d_in[1];
    const float* Wk = (const float*)d_in[2];
    const float* Wv = (const float*)d_in[3];
    const float* W1 = (const float*)d_in[4];
    const float* W2 = (const float*)d_in[5];
    float* out = (float*)d_out;

    // Scratch (bytes): Qp/Kp/fcp 16M each (4 slabs), Sp 16M (8 slabs), Gp 2M, PBp 2M
    const size_t QPB = 16777216, KPB = 16777216, FCPB = 16777216,
                 SPB = 16777216, GPB = 2097152, PBB = 2097152;
    const size_t need = QPB + KPB + FCPB + SPB + GPB + PBB;  // 68 MB

    float *Qp, *Kp, *fcp, *Sp, *Gp, *PBp;
    if (ws_size >= need) {
        char* w = (char*)d_ws;
        Qp  = (float*)w;  w += QPB;
        Kp  = (float*)w;  w += KPB;
        fcp = (float*)w;  w += FCPB;
        Sp  = (float*)w;  w += SPB;
        Gp  = (float*)w;  w += GPB;
        PBp = (float*)w;
    } else {
        // Fallback: fcout reads Qp/PBp/fcp while writing d_out -> those go in ws
        // (34 MB); Kp/Sp/Gp (dead before fcout) live in d_out (34 MB <= 64 MB).
        char* w = (char*)d_ws;
        Qp  = (float*)w;  w += QPB;
        fcp = (float*)w;  w += FCPB;
        PBp = (float*)w;
        char* o = (char*)d_out;
        Kp  = (float*)o;  o += KPB;
        Sp  = (float*)o;  o += SPB;
        Gp  = (float*)o;
    }

    // 1) Qp/Kp/fcp k-quarter partials (1024 blocks, 4/CU)
    qkf_kernel<<<dim3(256, 4), 256, 0, stream>>>(x, Wq, Wk, W1, Qp, Kp, fcp);

    // 2) Gpart[ks8][k][d] = W1 * Wv (batch-independent, 128 blocks)
    mm_nt<0, 2, 1, 1><<<dim3(1, 16, 8), 256, 0, stream>>>(
        W1, 1024, 0, 0,   Wv, 1024, 0, 0,
        Gp, 1024, 0, 65536L, 1024, 8);

    // 3) Sp[ks8][b][j][d] = (sum_4 Kp)^T * x  (1024 blocks)
    s_kernel<<<dim3(16, 8, 8), 256, 0, stream>>>(Kp, x, Sp);

    // 4) PBTpart[ks16][b][k][j] = (sum_8 Gp)[k,:] * (sum_8 Sp)[b][j,:]^T (128 blocks)
    mm_nt<0, 0, 8, 8><<<dim3(1, 1, 128), 256, 0, stream>>>(
        Gp, 1024, 0, 65536L,   Sp, 1024, 65536L, 524288L,
        PBp, 64, 4096L, 32768L, 1024, 16);

    // 5) fc = sum fcp + Qsum*PBsum^T; out = fc*W2^T  (256 blocks)
    fcout_kernel<<<dim3(256), 256, 0, stream>>>(Qp, PBp, fcp, W2, out);
}